// Round 11
// baseline (715.203 us; speedup 1.0000x reference)
//
#include <hip/hip_runtime.h>
#include <math.h>

#define CH 256

typedef short short8 __attribute__((ext_vector_type(8)));
typedef float f32x4 __attribute__((ext_vector_type(4)));

// f32 -> bf16 bits (RNE); adjacency values are small ints, exact
__device__ inline ushort f2bf(float f) {
  unsigned u = __float_as_uint(f);
  unsigned r = (u + 0x7FFFu + ((u >> 16) & 1u)) >> 16;
  return (ushort)r;
}

// async global->LDS, 16B per lane; LDS dest is wave-uniform base + lane*16
__device__ inline void gload16(const void* g, void* l) {
  __builtin_amdgcn_global_load_lds((const __attribute__((address_space(1))) void*)g,
                                   (__attribute__((address_space(3))) void*)l, 16, 0, 0);
}

// ---------------- build ----------------

__global__ void scatter_edges(const int* __restrict__ ei, int E, int n, float* __restrict__ A) {
  int e = blockIdx.x * blockDim.x + threadIdx.x;
  if (e < E) atomicAdd(&A[(size_t)ei[e] * n + ei[E + e]], 1.0f);
}

// ---------------- fused transpose + diag rule + column-degree ----------------
// Reads zn z-slices of In (stride zoff) and sums them (for K-split GEMM partials).
template <int DIAGMODE>
__global__ __launch_bounds__(256) void transpose_deg(const float* __restrict__ In, int n,
                                                     ushort* __restrict__ O, float* __restrict__ deg,
                                                     int zn, size_t zoff) {
  __shared__ float t[64][65];
  int j0 = blockIdx.x * 64, i0 = blockIdx.y * 64;
  int tx = threadIdx.x & 63, ty4 = threadIdx.x >> 6;
  float s = 0.f;
#pragma unroll
  for (int r = 0; r < 64; r += 4) {
    int gi = i0 + ty4 + r, gj = j0 + tx;
    size_t idx = (size_t)gi * n + gj;
    float v = In[idx];
    for (int z = 1; z < zn; ++z) v += In[idx + (size_t)z * zoff];
    if (gi == gj) v = (DIAGMODE == 1) ? 2.0f : ((v != 0.f) ? v : 2.0f);
    t[ty4 + r][tx] = v;
    s += v;
  }
  atomicAdd(&deg[j0 + tx], s);
  __syncthreads();
#pragma unroll
  for (int r = 0; r < 64; r += 4) {
    int c = ty4 + r;
    O[(size_t)(j0 + c) * n + i0 + tx] = f2bf(t[tx][c]);
  }
}

// ---------------- top-k via parallel rank-select ----------------
// Keys are distinct (index packed in low bits) -> output position == rank
// (= count of strictly-greater keys). Same total order as descending score
// with ascending-index tie-break (bit-identical to jax.lax.top_k ordering).
__global__ __launch_bounds__(256) void topk_rank(const float* __restrict__ sc, int n, int k,
                                                 int* __restrict__ perm, float* __restrict__ vals) {
  extern __shared__ unsigned long long kbuf[];   // n keys (n*8 bytes)
  __shared__ int red[4][64];
  int tid = threadIdx.x;
  for (int i = tid; i < n; i += 256) {
    unsigned u = __float_as_uint(sc[i]);
    u = (u & 0x80000000u) ? ~u : (u | 0x80000000u);   // order-preserving flip
    kbuf[i] = ((unsigned long long)u << 32) | (0xFFFFFFFFu - (unsigned)i);
  }
  __syncthreads();
  const int ti = tid & 63, tj = tid >> 6;
  const int i = blockIdx.x * 64 + ti;
  const unsigned long long ki = kbuf[i];
  int cnt = 0;
  const int q = n >> 2;
  const int jb = tj * q, je = jb + q;
#pragma unroll 4
  for (int j = jb; j < je; j += 2) {
    unsigned long long k0 = kbuf[j], k1 = kbuf[j + 1];   // wave-uniform, broadcast
    cnt += (k0 > ki) + (k1 > ki);
  }
  red[tj][ti] = cnt;
  __syncthreads();
  if (tid < 64) {
    int r = red[0][ti] + red[1][ti] + red[2][ti] + red[3][ti];
    if (r < k) { perm[r] = i; vals[r] = sc[i]; }
  }
}

// ---------------- fused augment-gathers + pool_x (one launch per level) ----------------
// blockIdx.x in [0, nbcvt)            : Arow[m][..] = bf16(sum_z Asrc[z][perm[m]][..]), diag->1
// blockIdx.x in [nbcvt, nbcvt+nbbf)   : Brow[m][..] = At[perm[m]][..] (bf16), diag->1
// blockIdx.x == nbcvt+nbbf            : xo[m][:] = xin[perm[m]][:] * vals[m]
__global__ __launch_bounds__(256) void gather_fused(const float* __restrict__ Asrc, int zn, size_t zoff,
                                                    const ushort* __restrict__ At,
                                                    const int* __restrict__ perm, int n,
                                                    ushort* __restrict__ Arow, ushort* __restrict__ Brow,
                                                    const float* __restrict__ xin,
                                                    const float* __restrict__ vals, float* __restrict__ xo,
                                                    int nbcvt, int nbbf) {
  int bx = blockIdx.x;
  int m = blockIdx.y;
  int src = perm[m];
  if (bx < nbcvt) {
    int k4 = (bx * 256 + threadIdx.x) * 4;
    float4 v = *(const float4*)&Asrc[(size_t)src * n + k4];
    for (int z = 1; z < zn; ++z) {
      float4 u = *(const float4*)&Asrc[(size_t)z * zoff + (size_t)src * n + k4];
      v.x += u.x; v.y += u.y; v.z += u.z; v.w += u.w;
    }
    if (src >= k4 && src < k4 + 4) ((float*)&v)[src - k4] = 1.0f;
    ushort4 o;
    o.x = f2bf(v.x); o.y = f2bf(v.y); o.z = f2bf(v.z); o.w = f2bf(v.w);
    *(ushort4*)&Arow[(size_t)m * n + k4] = o;
  } else if (bx < nbcvt + nbbf) {
    int k8 = ((bx - nbcvt) * 256 + threadIdx.x) * 8;
    uint4 v = *(const uint4*)&At[(size_t)src * n + k8];
    if (src >= k8 && src < k8 + 8) ((ushort*)&v)[src - k8] = 0x3F80;  // bf16(1.0)
    *(uint4*)&Brow[(size_t)m * n + k8] = v;
  } else {
    xo[(size_t)m * CH + threadIdx.x] = xin[(size_t)src * CH + threadIdx.x] * vals[m];
  }
}

// ---------------- unified bf16 MFMA NT GEMM, templated on BN ----------------
// C[m][n] = sum_{k in z-slice} Aop[m][k]*Bop[n][k]
// BN=128: waves own 64x64, 2-buffer 64KB, depth-1, vmcnt(8)/0 (augments, K-split).
// BN=64 : waves own 64x32, 3-buffer 72KB, depth-2, vmcnt(12/6/0) (agg GEMMs, N=CH).
// global_load_lds width-16 with SOURCE-side XOR swizzle + matching read XOR ->
// conflict-free both sides. K-split: blockIdx.z -> disjoint partial buffers.
// FUSED EPILOGUE (cnt != nullptr, agg path): after storing partials, blocks bump
// a per-row-tile device counter; the LAST of the 4*zn blocks for a row-tile
// re-reads the partials (L2-warm) and applies relu/bias/dinv + optional fused
// score (p,sc) or global-mean atomics (macc). Standard threadfence-reduction
// pattern -- no dispatch-order assumption (G16).

template <int BN>
__device__ inline void stage_tile(const ushort* ag, const ushort* bg, int ktOff,
                                  char* asb, char* bsb, int K) {
#pragma unroll
  for (int i = 0; i < 4; ++i)
    gload16(ag + (size_t)i * 32 * K + ktOff, asb + i * 4096);
#pragma unroll
  for (int i = 0; i < BN / 32; ++i)
    gload16(bg + (size_t)i * 32 * K + ktOff, bsb + i * 4096);
}

template <int BN>
__device__ inline void compute_tile(const ushort (*__restrict__ As)[64],
                                    const ushort (*__restrict__ Bs)[64],
                                    int wm, int wn, int lrow, int col0, int col1,
                                    f32x4 acc[4][BN / 32]) {
#pragma unroll
  for (int ks = 0; ks < 2; ++ks) {
    const int col = ks ? col1 : col0;
    short8 af[4], bf[BN / 32];
#pragma unroll
    for (int t = 0; t < 4; ++t)
      af[t] = *(const short8*)&As[wm + t * 16 + lrow][col];
#pragma unroll
    for (int t = 0; t < BN / 32; ++t)
      bf[t] = *(const short8*)&Bs[wn + t * 16 + lrow][col];
#pragma unroll
    for (int mt = 0; mt < 4; ++mt)
#pragma unroll
      for (int nt = 0; nt < BN / 32; ++nt)
        acc[mt][nt] = __builtin_amdgcn_mfma_f32_16x16x32_bf16(af[mt], bf[nt], acc[mt][nt], 0, 0, 0);
  }
}

template <int BN>
__global__ __launch_bounds__(256) void mfma_nt(const ushort* __restrict__ Aop,
                                               const ushort* __restrict__ Bop,
                                               float* __restrict__ C, int ldc,
                                               int K, int Ks, size_t zstride,
                                               int zn, unsigned* cnt, float* deg,
                                               const float* bias, float* xo,
                                               const float* pvec, float* sc, float* macc) {
  constexpr int NBUF = (BN == 128) ? 2 : 3;
  constexpr int NT = BN / 32;
  __shared__ ushort As[NBUF][128][64];
  __shared__ ushort Bs[NBUF][BN][64];
  const int tid = threadIdx.x;
  const int wave = tid >> 6, lane = tid & 63;
  const int wm = (wave & 1) * 64, wn = (wave >> 1) * (BN / 2);
  const int m0 = blockIdx.x * 128, n0 = blockIdx.y * BN;
  const int k0 = blockIdx.z * Ks;
  float* Cbase = C;
  C += (size_t)blockIdx.z * zstride;
  const int lrow = lane & 15;
  // read-side swizzle: LDS[row][slot] holds G[row][slot ^ (row&7)]; our rows have row&7 == lane&7
  const int q = lane >> 4;
  const int rx = lane & 7;
  const int col0 = ((q)     ^ rx) * 8;   // ks=0: logical slot q
  const int col1 = ((4 + q) ^ rx) * 8;   // ks=1: logical slot 4+q
  // stage-side: linear LDS dest; permute the GLOBAL source column so data lands swizzled.
  // staged row&7 == lane>>3 for every issue (wave*8 and i*32 are 0 mod 8)
  const int srow = wave * 8 + (lane >> 3);
  const int scol = ((lane & 7) ^ (lane >> 3)) * 8;
  const ushort* ag = Aop + (size_t)(m0 + srow) * K + k0 + scol;
  const ushort* bg = Bop + (size_t)(n0 + srow) * K + k0 + scol;
  f32x4 acc[4][NT] = {};

  const int nk = Ks >> 6;   // >= 2 for every launch config

#define STAGE(bi, idx) stage_tile<BN>(ag, bg, (idx) * 64, \
    (char*)&As[bi][0][0] + wave * 1024, (char*)&Bs[bi][0][0] + wave * 1024, K)

  if constexpr (NBUF == 2) {
    // depth-1 pipeline, 8 loads/stage
    STAGE(0, 0);
    if (1 < nk) STAGE(1, 1);
    int bi = 0;
    for (int t = 0; t < nk - 1; ++t) {
      asm volatile("s_waitcnt vmcnt(8)" ::: "memory");   // next stage may stay in flight
      __builtin_amdgcn_s_barrier();
      __builtin_amdgcn_sched_barrier(0);
      compute_tile<BN>(As[bi], Bs[bi], wm, wn, lrow, col0, col1, acc);
      __builtin_amdgcn_sched_barrier(0);
      __builtin_amdgcn_s_barrier();
      if (t + 2 < nk) STAGE(bi, t + 2);
      bi ^= 1;
    }
    asm volatile("s_waitcnt vmcnt(0)" ::: "memory");
    __builtin_amdgcn_s_barrier();
    __builtin_amdgcn_sched_barrier(0);
    compute_tile<BN>(As[bi], Bs[bi], wm, wn, lrow, col0, col1, acc);
  } else {
    // depth-2 pipeline, 6 loads/stage (round-6-proven)
    STAGE(0, 0);
    if (1 < nk) STAGE(1, 1);
    if (2 < nk) STAGE(2, 2);
    int bi = 0;
    for (int t = 0; t < nk - 2; ++t) {
      asm volatile("s_waitcnt vmcnt(12)" ::: "memory");
      __builtin_amdgcn_s_barrier();
      __builtin_amdgcn_sched_barrier(0);
      compute_tile<BN>(As[bi], Bs[bi], wm, wn, lrow, col0, col1, acc);
      __builtin_amdgcn_sched_barrier(0);
      __builtin_amdgcn_s_barrier();
      if (t + 3 < nk) STAGE(bi, t + 3);
      bi = (bi + 1 < 3) ? bi + 1 : 0;
    }
    asm volatile("s_waitcnt vmcnt(6)" ::: "memory");
    __builtin_amdgcn_s_barrier();
    __builtin_amdgcn_sched_barrier(0);
    compute_tile<BN>(As[bi], Bs[bi], wm, wn, lrow, col0, col1, acc);
    bi = (bi + 1 < 3) ? bi + 1 : 0;
    asm volatile("s_waitcnt vmcnt(0)" ::: "memory");
    __builtin_amdgcn_s_barrier();
    __builtin_amdgcn_sched_barrier(0);
    compute_tile<BN>(As[bi], Bs[bi], wm, wn, lrow, col0, col1, acc);
  }
#undef STAGE

  const int crow = (lane >> 4) * 4, ccol = lane & 15;
#pragma unroll
  for (int mt = 0; mt < 4; ++mt)
#pragma unroll
    for (int nt = 0; nt < NT; ++nt) {
      int gm = m0 + wm + mt * 16 + crow;
      int gn = n0 + wn + nt * 16 + ccol;
#pragma unroll
      for (int r = 0; r < 4; ++r)
        C[(size_t)(gm + r) * ldc + gn] = acc[mt][nt][r];
    }

  // ---- fused epilogue: last of the gridDim.y*gridDim.z blocks for this
  //      row-tile reduces partials + applies relu/bias/dinv (+score / +mean) ----
  if (cnt) {
    __threadfence();                       // release partial stores (device scope)
    __shared__ unsigned done;
    if (tid == 0) done = atomicAdd(&cnt[blockIdx.x], 1u);
    __syncthreads();
    if (done == gridDim.y * gridDim.z - 1) {
      __threadfence();                     // acquire other blocks' stores
      const int w = tid >> 6, c4 = tid & 63;
      float4 msum = {0.f, 0.f, 0.f, 0.f};
      const float4 b = ((const float4*)bias)[c4];
      float4 pv;
      float pn = 0.f;
      if (pvec) {
        pv = ((const float4*)pvec)[c4];
        pn = pv.x * pv.x + pv.y * pv.y + pv.z * pv.z + pv.w * pv.w;
        for (int off2 = 32; off2; off2 >>= 1) pn += __shfl_down(pn, off2);
        pn = __shfl(pn, 0);
      }
      for (int r = 0; r < 32; ++r) {
        const int m = m0 + r * 4 + w;
        float d = deg[m];
        float s = (d > 0.f) ? 1.0f / sqrtf(d) : 0.f;
        float4 v = *(const float4*)&Cbase[(size_t)m * ldc + c4 * 4];
        for (int z = 1; z < zn; ++z) {
          float4 u = *(const float4*)&Cbase[(size_t)z * zstride + (size_t)m * ldc + c4 * 4];
          v.x += u.x; v.y += u.y; v.z += u.z; v.w += u.w;
        }
        v.x = fmaxf(fmaf(v.x, s, b.x), 0.f);
        v.y = fmaxf(fmaf(v.y, s, b.y), 0.f);
        v.z = fmaxf(fmaf(v.z, s, b.z), 0.f);
        v.w = fmaxf(fmaf(v.w, s, b.w), 0.f);
        if (xo) ((float4*)xo)[(size_t)m * 64 + c4] = v;
        if (c4 == 0) deg[m] = 0.f;         // pre-zero for next level
        if (pvec) {
          float dot = v.x * pv.x + v.y * pv.y + v.z * pv.z + v.w * pv.w;
          for (int off2 = 32; off2; off2 >>= 1) dot += __shfl_down(dot, off2);
          if (c4 == 0) sc[m] = tanhf(dot / sqrtf(pn));
        }
        if (macc) { msum.x += v.x; msum.y += v.y; msum.z += v.z; msum.w += v.w; }
      }
      if (macc) {
        __shared__ float4 ssum[4][64];
        ssum[w][c4] = msum;
        __syncthreads();
        if (w == 0) {
          float4 t0 = ssum[0][c4], t1 = ssum[1][c4], t2 = ssum[2][c4], t3 = ssum[3][c4];
          atomicAdd(&macc[c4 * 4 + 0], t0.x + t1.x + t2.x + t3.x);
          atomicAdd(&macc[c4 * 4 + 1], t0.y + t1.y + t2.y + t3.y);
          atomicAdd(&macc[c4 * 4 + 2], t0.z + t1.z + t2.z + t3.z);
          atomicAdd(&macc[c4 * 4 + 3], t0.w + t1.w + t2.w + t3.w);
        }
      }
    }
  }
}

// ---------------- fp32 xW GEMM -> Gt[n][m] = bf16(dinv[m]*(x@W)[m][n]) ----------------
__global__ __launch_bounds__(256) void xw_gemm(const float* __restrict__ Am,
                                               const float* __restrict__ Bm,
                                               ushort* __restrict__ Gt,
                                               int M, const float* __restrict__ deg) {
  __shared__ float As[16][64];
  __shared__ float Bs[16][64];
  const int tid = threadIdx.x;
  const int m0 = blockIdx.x * 64, n0 = blockIdx.y * 64;
  float acc[4][4] = {{0.f}};
  const int tm = tid & 15, tn = tid >> 4;

  for (int kt = 0; kt < CH; kt += 16) {
    __syncthreads();
    {
      int mm = tid >> 2, kq = (tid & 3) * 4;
      float4 v = *(const float4*)(Am + (size_t)(m0 + mm) * CH + kt + kq);
      As[kq + 0][mm] = v.x; As[kq + 1][mm] = v.y; As[kq + 2][mm] = v.z; As[kq + 3][mm] = v.w;
    }
#pragma unroll
    for (int r = 0; r < 4; ++r) {
      int idx = tid + r * 256;
      int kk = idx >> 6, nn = idx & 63;
      Bs[kk][nn] = Bm[(size_t)(kt + kk) * CH + (n0 + nn)];
    }
    __syncthreads();
#pragma unroll
    for (int kk = 0; kk < 16; ++kk) {
      float4 a = *(const float4*)&As[kk][tm * 4];
      float4 b = *(const float4*)&Bs[kk][tn * 4];
      acc[0][0] = fmaf(a.x, b.x, acc[0][0]);
      acc[0][1] = fmaf(a.x, b.y, acc[0][1]);
      acc[0][2] = fmaf(a.x, b.z, acc[0][2]);
      acc[0][3] = fmaf(a.x, b.w, acc[0][3]);
      acc[1][0] = fmaf(a.y, b.x, acc[1][0]);
      acc[1][1] = fmaf(a.y, b.y, acc[1][1]);
      acc[1][2] = fmaf(a.y, b.z, acc[1][2]);
      acc[1][3] = fmaf(a.y, b.w, acc[1][3]);
      acc[2][0] = fmaf(a.z, b.x, acc[2][0]);
      acc[2][1] = fmaf(a.z, b.y, acc[2][1]);
      acc[2][2] = fmaf(a.z, b.z, acc[2][2]);
      acc[2][3] = fmaf(a.z, b.w, acc[2][3]);
      acc[3][0] = fmaf(a.w, b.x, acc[3][0]);
      acc[3][1] = fmaf(a.w, b.y, acc[3][1]);
      acc[3][2] = fmaf(a.w, b.z, acc[3][2]);
      acc[3][3] = fmaf(a.w, b.w, acc[3][3]);
    }
  }

#pragma unroll
  for (int ii = 0; ii < 4; ++ii) {
    int m = m0 + tm * 4 + ii;
    float d = deg[m];
    float s = (d > 0.f) ? 1.0f / sqrtf(d) : 0.f;
#pragma unroll
    for (int jj = 0; jj < 4; ++jj) {
      int n = n0 + tn * 4 + jj;
      Gt[(size_t)n * M + m] = f2bf(s * acc[ii][jj]);
    }
  }
}

// ---------------- readout ----------------

__global__ __launch_bounds__(256) void finalize2(const float* __restrict__ macc, int nr,
                                                 const float* __restrict__ wc,
                                                 const float* __restrict__ bc,
                                                 float* __restrict__ out) {
  __shared__ float semb[256];
  __shared__ float red[256];
  __shared__ float slog[16];
  int c = threadIdx.x;
  float emb = macc[c] / (float)nr;
  red[c] = emb * emb;
  __syncthreads();
  for (int off = 128; off; off >>= 1) {
    if (c < off) red[c] += red[c + off];
    __syncthreads();
  }
  float denom = fmaxf(sqrtf(red[0]), 1e-12f);
  float en = emb / denom;
  semb[c] = en;
  out[c] = en;
  __syncthreads();
  if (c < 10) {
    float l = bc[c];
    for (int t = 0; t < CH; ++t) l = fmaf(semb[t], wc[c * CH + t], l);
    slog[c] = l;
  }
  __syncthreads();
  if (c == 0) {
    float mx = slog[0];
    for (int j = 1; j < 10; ++j) mx = fmaxf(mx, slog[j]);
    float se = 0.f;
    for (int j = 0; j < 10; ++j) se += expf(slog[j] - mx);
    float lse = mx + logf(se);
    for (int j = 0; j < 10; ++j) out[CH + j] = slog[j] - lse;
  }
}

// ---------------- orchestration ----------------

extern "C" void kernel_launch(void* const* d_in, const int* in_sizes, int n_in,
                              void* d_out, int out_size, void* d_ws, size_t ws_size,
                              hipStream_t stream) {
  const float* x  = (const float*)d_in[0];
  const int*   ei = (const int*)d_in[1];
  const float* w0 = (const float*)d_in[2];
  const float* b0 = (const float*)d_in[3];
  const float* w1 = (const float*)d_in[4];
  const float* b1 = (const float*)d_in[5];
  const float* w2 = (const float*)d_in[6];
  const float* b2 = (const float*)d_in[7];
  const float* p1 = (const float*)d_in[8];
  const float* p2 = (const float*)d_in[9];
  const float* wc = (const float*)d_in[10];
  const float* bc = (const float*)d_in[11];
  float* out = (float*)d_out;
  const int N0 = 4096, K1 = 2048, K2 = 1024;
  int E = in_sizes[1] / 2;

  float* W = (float*)d_ws;
  size_t off = 0;
  float* A    = W + off; off += (size_t)N0 * N0;                  // fp32 adj; region reused later:
                                                                  //   Brow (bf16 gathered rows) at A[0..]
                                                                  //   Paux (aug z-partials) at A+8M floats (32MB, to end of A)
  // deg/cnt/macc live contiguously after A -> one memset covers all
  float* deg  = W + off;                                          // 4096 floats
  unsigned* cnt0 = (unsigned*)(deg + 4096);                       // 32 + 16 + 8 counters (pad 64)
  unsigned* cnt1 = cnt0 + 32;
  unsigned* cnt2 = cnt1 + 16;
  float* macc = (float*)(cnt0 + 64);                              // 256 floats
  off += (size_t)K1 * K1;                                         // (old-Pa slot, mostly spare)
  ushort* At  = (ushort*)(W + off); off += (size_t)N0 * N0 / 2;   // bf16 transposed adj (per level)
  ushort* Arow = (ushort*)(W + off); off += (size_t)K1 * N0 / 2;  // bf16 gathered rows
  ushort* Brow = (ushort*)A;                                      // aliases A (dead rows consumed first)
  float* Paux = A + (size_t)8 * 1024 * 1024;  // aug partials: augL1 2x2048^2, augL2 8x1024^2 (both 32MB)
  float* Cred = (float*)Arow;  // aliases Arow: agg partials (zn x M x CH), live only within the agg kernel
  float* x0   = W + off; off += (size_t)N0 * CH;
  ushort* Gt  = (ushort*)(W + off); off += (size_t)N0 * CH / 2;
  float* xp  = W + off; off += (size_t)K1 * CH;
  float* x1  = W + off; off += (size_t)K1 * CH;
  float* sc  = W + off; off += 4096;
  float* vals = W + off; off += 4096;
  int* perm1 = (int*)(W + off); off += 4096;
  int* perm2 = (int*)(W + off); off += 4096;

  // ---- build adjacency (+ zero deg/cnt/macc in the same memset) ----
  hipMemsetAsync(A, 0, ((size_t)N0 * N0 + 4096 + 64 + 256) * 4, stream);
  scatter_edges<<<(E + 255) / 256, 256, 0, stream>>>(ei, E, N0, A);

  // ---- GCN 0 ----
  transpose_deg<0><<<dim3(N0 / 64, N0 / 64), 256, 0, stream>>>(A, N0, At, deg, 1, 0);
  xw_gemm<<<dim3(N0 / 64, CH / 64), 256, 0, stream>>>(x, w0, Gt, N0, deg);
  mfma_nt<64><<<dim3(N0 / 128, CH / 64, 4), 256, 0, stream>>>(
      At, Gt, Cred, CH, N0, N0 / 4, (size_t)N0 * CH,
      4, cnt0, deg, b0, x0, p1, sc, nullptr);

  // ---- pool 1 ----
  topk_rank<<<N0 / 64, 256, N0 * 8, stream>>>(sc, N0, K1, perm1, vals);

  // ---- augment L1 gathers + pool_x (fused), then Paux(z=2) K-split GEMM ----
  gather_fused<<<dim3(N0 / 1024 + N0 / 2048 + 1, K1), 256, 0, stream>>>(
      A, 1, 0, At, perm1, N0, Arow, Brow, x0, vals, xp, N0 / 1024, N0 / 2048);
  mfma_nt<128><<<dim3(K1 / 128, K1 / 128, 2), 256, 0, stream>>>(
      Arow, Brow, Paux, K1, N0, N0 / 2, (size_t)K1 * K1,
      0, nullptr, nullptr, nullptr, nullptr, nullptr, nullptr, nullptr);

  // ---- GCN 1 (transpose sums the 2 aug partial slices; deg pre-zeroed by L0 fused epi) ----
  transpose_deg<1><<<dim3(K1 / 64, K1 / 64), 256, 0, stream>>>(Paux, K1, At, deg, 2, (size_t)K1 * K1);
  xw_gemm<<<dim3(K1 / 64, CH / 64), 256, 0, stream>>>(xp, w1, Gt, K1, deg);
  mfma_nt<64><<<dim3(K1 / 128, CH / 64, 8), 256, 0, stream>>>(
      At, Gt, Cred, CH, K1, K1 / 8, (size_t)K1 * CH,
      8, cnt1, deg, b1, x1, p2, sc, nullptr);

  // ---- pool 2 ----
  topk_rank<<<K1 / 64, 256, K1 * 8, stream>>>(sc, K1, K2, perm2, vals);

  // ---- augment L2 gathers (sum 2 L1-partial slices) + pool_x (fused); z=8 K-split out ----
  gather_fused<<<dim3(K1 / 1024 + K1 / 2048 + 1, K2), 256, 0, stream>>>(
      Paux, 2, (size_t)K1 * K1, At, perm2, K1, Arow, Brow, x1, vals, xp, K1 / 1024, K1 / 2048);
  mfma_nt<128><<<dim3(K2 / 128, K2 / 128, 8), 256, 0, stream>>>(
      Arow, Brow, Paux, K2, K1, K1 / 8, (size_t)K2 * K2,
      0, nullptr, nullptr, nullptr, nullptr, nullptr, nullptr, nullptr);

  // ---- GCN 2 (transpose sums the 8 aug partial slices; fused epi feeds macc directly) ----
  transpose_deg<1><<<dim3(K2 / 64, K2 / 64), 256, 0, stream>>>(Paux, K2, At, deg, 8, (size_t)K2 * K2);
  xw_gemm<<<dim3(K2 / 64, CH / 64), 256, 0, stream>>>(xp, w2, Gt, K2, deg);
  mfma_nt<64><<<dim3(K2 / 128, CH / 64, 8), 256, 0, stream>>>(
      At, Gt, Cred, CH, K2, K2 / 8, (size_t)K2 * CH,
      8, cnt2, deg, b2, nullptr, nullptr, nullptr, macc);

  // ---- readout (macc filled by L2 fused epilogue) ----
  finalize2<<<1, 256, 0, stream>>>(macc, K2, wc, bc, out);
}

// Round 12
// 380.706 us; speedup vs baseline: 1.8786x; 1.8786x over previous
//
#include <hip/hip_runtime.h>
#include <math.h>

#define CH 256

typedef short short8 __attribute__((ext_vector_type(8)));
typedef float f32x4 __attribute__((ext_vector_type(4)));

// f32 -> bf16 bits (RNE); adjacency values are small ints, exact
__device__ inline ushort f2bf(float f) {
  unsigned u = __float_as_uint(f);
  unsigned r = (u + 0x7FFFu + ((u >> 16) & 1u)) >> 16;
  return (ushort)r;
}

// async global->LDS, 16B per lane; LDS dest is wave-uniform base + lane*16
__device__ inline void gload16(const void* g, void* l) {
  __builtin_amdgcn_global_load_lds((const __attribute__((address_space(1))) void*)g,
                                   (__attribute__((address_space(3))) void*)l, 16, 0, 0);
}

// ---------------- build ----------------

__global__ void scatter_edges(const int* __restrict__ ei, int E, int n, float* __restrict__ A) {
  int e = blockIdx.x * blockDim.x + threadIdx.x;
  if (e < E) atomicAdd(&A[(size_t)ei[e] * n + ei[E + e]], 1.0f);
}

// ---------------- fused transpose + diag rule + column-degree ----------------
// Reads zn z-slices of In (stride zoff) and sums them (for K-split GEMM partials).
template <int DIAGMODE>
__global__ __launch_bounds__(256) void transpose_deg(const float* __restrict__ In, int n,
                                                     ushort* __restrict__ O, float* __restrict__ deg,
                                                     int zn, size_t zoff) {
  __shared__ float t[64][65];
  int j0 = blockIdx.x * 64, i0 = blockIdx.y * 64;
  int tx = threadIdx.x & 63, ty4 = threadIdx.x >> 6;
  float s = 0.f;
#pragma unroll
  for (int r = 0; r < 64; r += 4) {
    int gi = i0 + ty4 + r, gj = j0 + tx;
    size_t idx = (size_t)gi * n + gj;
    float v = In[idx];
    for (int z = 1; z < zn; ++z) v += In[idx + (size_t)z * zoff];
    if (gi == gj) v = (DIAGMODE == 1) ? 2.0f : ((v != 0.f) ? v : 2.0f);
    t[ty4 + r][tx] = v;
    s += v;
  }
  atomicAdd(&deg[j0 + tx], s);
  __syncthreads();
#pragma unroll
  for (int r = 0; r < 64; r += 4) {
    int c = ty4 + r;
    O[(size_t)(j0 + c) * n + i0 + tx] = f2bf(t[tx][c]);
  }
}

// ---------------- top-k via parallel rank-select ----------------
// Keys are distinct (index packed in low bits) -> output position == rank
// (= count of strictly-greater keys). Same total order as descending score
// with ascending-index tie-break (bit-identical to jax.lax.top_k ordering).
__global__ __launch_bounds__(256) void topk_rank(const float* __restrict__ sc, int n, int k,
                                                 int* __restrict__ perm, float* __restrict__ vals) {
  extern __shared__ unsigned long long kbuf[];   // n keys (n*8 bytes)
  __shared__ int red[4][64];
  int tid = threadIdx.x;
  for (int i = tid; i < n; i += 256) {
    unsigned u = __float_as_uint(sc[i]);
    u = (u & 0x80000000u) ? ~u : (u | 0x80000000u);   // order-preserving flip
    kbuf[i] = ((unsigned long long)u << 32) | (0xFFFFFFFFu - (unsigned)i);
  }
  __syncthreads();
  const int ti = tid & 63, tj = tid >> 6;
  const int i = blockIdx.x * 64 + ti;
  const unsigned long long ki = kbuf[i];
  int cnt = 0;
  const int q = n >> 2;
  const int jb = tj * q, je = jb + q;
#pragma unroll 4
  for (int j = jb; j < je; j += 2) {
    unsigned long long k0 = kbuf[j], k1 = kbuf[j + 1];   // wave-uniform, broadcast
    cnt += (k0 > ki) + (k1 > ki);
  }
  red[tj][ti] = cnt;
  __syncthreads();
  if (tid < 64) {
    int r = red[0][ti] + red[1][ti] + red[2][ti] + red[3][ti];
    if (r < k) { perm[r] = i; vals[r] = sc[i]; }
  }
}

// ---------------- fused augment-gathers + pool_x (one launch per level) ----------------
// blockIdx.x in [0, nbcvt)            : Arow[m][..] = bf16(sum_z Asrc[z][perm[m]][..]), diag->1
// blockIdx.x in [nbcvt, nbcvt+nbbf)   : Brow[m][..] = At[perm[m]][..] (bf16), diag->1
// blockIdx.x == nbcvt+nbbf            : xo[m][:] = xin[perm[m]][:] * vals[m]
__global__ __launch_bounds__(256) void gather_fused(const float* __restrict__ Asrc, int zn, size_t zoff,
                                                    const ushort* __restrict__ At,
                                                    const int* __restrict__ perm, int n,
                                                    ushort* __restrict__ Arow, ushort* __restrict__ Brow,
                                                    const float* __restrict__ xin,
                                                    const float* __restrict__ vals, float* __restrict__ xo,
                                                    int nbcvt, int nbbf) {
  int bx = blockIdx.x;
  int m = blockIdx.y;
  int src = perm[m];
  if (bx < nbcvt) {
    int k4 = (bx * 256 + threadIdx.x) * 4;
    float4 v = *(const float4*)&Asrc[(size_t)src * n + k4];
    for (int z = 1; z < zn; ++z) {
      float4 u = *(const float4*)&Asrc[(size_t)z * zoff + (size_t)src * n + k4];
      v.x += u.x; v.y += u.y; v.z += u.z; v.w += u.w;
    }
    if (src >= k4 && src < k4 + 4) ((float*)&v)[src - k4] = 1.0f;
    ushort4 o;
    o.x = f2bf(v.x); o.y = f2bf(v.y); o.z = f2bf(v.z); o.w = f2bf(v.w);
    *(ushort4*)&Arow[(size_t)m * n + k4] = o;
  } else if (bx < nbcvt + nbbf) {
    int k8 = ((bx - nbcvt) * 256 + threadIdx.x) * 8;
    uint4 v = *(const uint4*)&At[(size_t)src * n + k8];
    if (src >= k8 && src < k8 + 8) ((ushort*)&v)[src - k8] = 0x3F80;  // bf16(1.0)
    *(uint4*)&Brow[(size_t)m * n + k8] = v;
  } else {
    xo[(size_t)m * CH + threadIdx.x] = xin[(size_t)src * CH + threadIdx.x] * vals[m];
  }
}

// ---------------- unified bf16 MFMA NT GEMM, templated on BN ----------------
// C[m][n] = sum_{k in z-slice} Aop[m][k]*Bop[n][k]
// BN=128: waves own 64x64, 2-buffer 64KB, depth-1, vmcnt(8)/0 (augments, K-split).
// BN=64 : waves own 64x32, 3-buffer 72KB, depth-2, vmcnt(12/6/0) (agg GEMMs, N=CH).
// global_load_lds width-16 with SOURCE-side XOR swizzle (linear LDS dest)
// + matching XOR on ds_read cols -> conflict-free both sides.
// K-split: blockIdx.z -> disjoint partial buffers (consumers sum slices).

template <int BN>
__device__ inline void stage_tile(const ushort* ag, const ushort* bg, int ktOff,
                                  char* asb, char* bsb, int K) {
#pragma unroll
  for (int i = 0; i < 4; ++i)
    gload16(ag + (size_t)i * 32 * K + ktOff, asb + i * 4096);
#pragma unroll
  for (int i = 0; i < BN / 32; ++i)
    gload16(bg + (size_t)i * 32 * K + ktOff, bsb + i * 4096);
}

template <int BN>
__device__ inline void compute_tile(const ushort (*__restrict__ As)[64],
                                    const ushort (*__restrict__ Bs)[64],
                                    int wm, int wn, int lrow, int col0, int col1,
                                    f32x4 acc[4][BN / 32]) {
#pragma unroll
  for (int ks = 0; ks < 2; ++ks) {
    const int col = ks ? col1 : col0;
    short8 af[4], bf[BN / 32];
#pragma unroll
    for (int t = 0; t < 4; ++t)
      af[t] = *(const short8*)&As[wm + t * 16 + lrow][col];
#pragma unroll
    for (int t = 0; t < BN / 32; ++t)
      bf[t] = *(const short8*)&Bs[wn + t * 16 + lrow][col];
#pragma unroll
    for (int mt = 0; mt < 4; ++mt)
#pragma unroll
      for (int nt = 0; nt < BN / 32; ++nt)
        acc[mt][nt] = __builtin_amdgcn_mfma_f32_16x16x32_bf16(af[mt], bf[nt], acc[mt][nt], 0, 0, 0);
  }
}

template <int BN>
__global__ __launch_bounds__(256) void mfma_nt(const ushort* __restrict__ Aop,
                                               const ushort* __restrict__ Bop,
                                               float* __restrict__ C, int ldc,
                                               int K, int Ks, size_t zstride) {
  constexpr int NBUF = (BN == 128) ? 2 : 3;
  constexpr int NT = BN / 32;
  __shared__ ushort As[NBUF][128][64];
  __shared__ ushort Bs[NBUF][BN][64];
  const int tid = threadIdx.x;
  const int wave = tid >> 6, lane = tid & 63;
  const int wm = (wave & 1) * 64, wn = (wave >> 1) * (BN / 2);
  const int m0 = blockIdx.x * 128, n0 = blockIdx.y * BN;
  const int k0 = blockIdx.z * Ks;
  C += (size_t)blockIdx.z * zstride;
  const int lrow = lane & 15;
  // read-side swizzle: LDS[row][slot] holds G[row][slot ^ (row&7)]; our rows have row&7 == lane&7
  const int q = lane >> 4;
  const int rx = lane & 7;
  const int col0 = ((q)     ^ rx) * 8;   // ks=0: logical slot q
  const int col1 = ((4 + q) ^ rx) * 8;   // ks=1: logical slot 4+q
  // stage-side: linear LDS dest; permute the GLOBAL source column so data lands swizzled.
  // staged row&7 == lane>>3 for every issue (wave*8 and i*32 are 0 mod 8)
  const int srow = wave * 8 + (lane >> 3);
  const int scol = ((lane & 7) ^ (lane >> 3)) * 8;
  const ushort* ag = Aop + (size_t)(m0 + srow) * K + k0 + scol;
  const ushort* bg = Bop + (size_t)(n0 + srow) * K + k0 + scol;
  f32x4 acc[4][NT] = {};

  const int nk = Ks >> 6;   // >= 2 for every launch config

#define STAGE(bi, idx) stage_tile<BN>(ag, bg, (idx) * 64, \
    (char*)&As[bi][0][0] + wave * 1024, (char*)&Bs[bi][0][0] + wave * 1024, K)

  if constexpr (NBUF == 2) {
    // depth-1 pipeline, 8 loads/stage
    STAGE(0, 0);
    if (1 < nk) STAGE(1, 1);
    int bi = 0;
    for (int t = 0; t < nk - 1; ++t) {
      asm volatile("s_waitcnt vmcnt(8)" ::: "memory");   // next stage may stay in flight
      __builtin_amdgcn_s_barrier();
      __builtin_amdgcn_sched_barrier(0);
      compute_tile<BN>(As[bi], Bs[bi], wm, wn, lrow, col0, col1, acc);
      __builtin_amdgcn_sched_barrier(0);
      __builtin_amdgcn_s_barrier();
      if (t + 2 < nk) STAGE(bi, t + 2);
      bi ^= 1;
    }
    asm volatile("s_waitcnt vmcnt(0)" ::: "memory");
    __builtin_amdgcn_s_barrier();
    __builtin_amdgcn_sched_barrier(0);
    compute_tile<BN>(As[bi], Bs[bi], wm, wn, lrow, col0, col1, acc);
  } else {
    // depth-2 pipeline, 6 loads/stage (round-6-proven)
    STAGE(0, 0);
    if (1 < nk) STAGE(1, 1);
    if (2 < nk) STAGE(2, 2);
    int bi = 0;
    for (int t = 0; t < nk - 2; ++t) {
      asm volatile("s_waitcnt vmcnt(12)" ::: "memory");
      __builtin_amdgcn_s_barrier();
      __builtin_amdgcn_sched_barrier(0);
      compute_tile<BN>(As[bi], Bs[bi], wm, wn, lrow, col0, col1, acc);
      __builtin_amdgcn_sched_barrier(0);
      __builtin_amdgcn_s_barrier();
      if (t + 3 < nk) STAGE(bi, t + 3);
      bi = (bi + 1 < 3) ? bi + 1 : 0;
    }
    asm volatile("s_waitcnt vmcnt(6)" ::: "memory");
    __builtin_amdgcn_s_barrier();
    __builtin_amdgcn_sched_barrier(0);
    compute_tile<BN>(As[bi], Bs[bi], wm, wn, lrow, col0, col1, acc);
    bi = (bi + 1 < 3) ? bi + 1 : 0;
    asm volatile("s_waitcnt vmcnt(0)" ::: "memory");
    __builtin_amdgcn_s_barrier();
    __builtin_amdgcn_sched_barrier(0);
    compute_tile<BN>(As[bi], Bs[bi], wm, wn, lrow, col0, col1, acc);
  }
#undef STAGE

  const int crow = (lane >> 4) * 4, ccol = lane & 15;
#pragma unroll
  for (int mt = 0; mt < 4; ++mt)
#pragma unroll
    for (int nt = 0; nt < NT; ++nt) {
      int gm = m0 + wm + mt * 16 + crow;
      int gn = n0 + wn + nt * 16 + ccol;
#pragma unroll
      for (int r = 0; r < 4; ++r)
        C[(size_t)(gm + r) * ldc + gn] = acc[mt][nt][r];
    }
}

// xo[m][c]=relu(dinv[m]*sum_z Cred_z+bias); optional fused score:
// sc[m]=tanh(dot(xo[m],p)/||p||). one wave per row (64 lanes x float4 = 256 ch).
// Also zeroes deg[m] after use (same wave that read it -- race-free), so the
// next level's transpose_deg needs no memset; optionally block 0 zeroes mclr[256].
__global__ void agg_epilogue(const float* __restrict__ Cred, size_t zstride, int zn,
                             float* __restrict__ deg,
                             const float* __restrict__ bias, float* __restrict__ xo,
                             const float* __restrict__ p, float* __restrict__ sc,
                             float* __restrict__ mclr) {
  int idx = blockIdx.x * 256 + threadIdx.x;
  int c4 = idx & 63;
  int m = idx >> 6;
  float d = deg[m];
  float s = (d > 0.f) ? 1.0f / sqrtf(d) : 0.f;
  if ((threadIdx.x & 63) == 0) deg[m] = 0.f;   // pre-zero for next level (after own read)
  if (mclr && blockIdx.x == 0) mclr[threadIdx.x] = 0.f;
  float4 v = ((const float4*)Cred)[idx];
  for (int z = 1; z < zn; ++z) {
    float4 u = ((const float4*)(Cred + (size_t)z * zstride))[idx];
    v.x += u.x; v.y += u.y; v.z += u.z; v.w += u.w;
  }
  float4 b = ((const float4*)bias)[c4];
  v.x = fmaxf(fmaf(v.x, s, b.x), 0.f);
  v.y = fmaxf(fmaf(v.y, s, b.y), 0.f);
  v.z = fmaxf(fmaf(v.z, s, b.z), 0.f);
  v.w = fmaxf(fmaf(v.w, s, b.w), 0.f);
  ((float4*)xo)[idx] = v;
  if (p) {
    float4 pv = ((const float4*)p)[c4];
    float dot = v.x * pv.x + v.y * pv.y + v.z * pv.z + v.w * pv.w;
    float pn  = pv.x * pv.x + pv.y * pv.y + pv.z * pv.z + pv.w * pv.w;
    for (int off = 32; off; off >>= 1) {
      dot += __shfl_down(dot, off);
      pn  += __shfl_down(pn, off);
    }
    if ((threadIdx.x & 63) == 0) sc[m] = tanhf(dot / sqrtf(pn));
  }
}

// ---------------- fp32 xW GEMM -> Gt[n][m] = bf16(dinv[m]*(x@W)[m][n]) ----------------
__global__ __launch_bounds__(256) void xw_gemm(const float* __restrict__ Am,
                                               const float* __restrict__ Bm,
                                               ushort* __restrict__ Gt,
                                               int M, const float* __restrict__ deg) {
  __shared__ float As[16][64];
  __shared__ float Bs[16][64];
  const int tid = threadIdx.x;
  const int m0 = blockIdx.x * 64, n0 = blockIdx.y * 64;
  float acc[4][4] = {{0.f}};
  const int tm = tid & 15, tn = tid >> 4;

  for (int kt = 0; kt < CH; kt += 16) {
    __syncthreads();
    {
      int mm = tid >> 2, kq = (tid & 3) * 4;
      float4 v = *(const float4*)(Am + (size_t)(m0 + mm) * CH + kt + kq);
      As[kq + 0][mm] = v.x; As[kq + 1][mm] = v.y; As[kq + 2][mm] = v.z; As[kq + 3][mm] = v.w;
    }
#pragma unroll
    for (int r = 0; r < 4; ++r) {
      int idx = tid + r * 256;
      int kk = idx >> 6, nn = idx & 63;
      Bs[kk][nn] = Bm[(size_t)(kt + kk) * CH + (n0 + nn)];
    }
    __syncthreads();
#pragma unroll
    for (int kk = 0; kk < 16; ++kk) {
      float4 a = *(const float4*)&As[kk][tm * 4];
      float4 b = *(const float4*)&Bs[kk][tn * 4];
      acc[0][0] = fmaf(a.x, b.x, acc[0][0]);
      acc[0][1] = fmaf(a.x, b.y, acc[0][1]);
      acc[0][2] = fmaf(a.x, b.z, acc[0][2]);
      acc[0][3] = fmaf(a.x, b.w, acc[0][3]);
      acc[1][0] = fmaf(a.y, b.x, acc[1][0]);
      acc[1][1] = fmaf(a.y, b.y, acc[1][1]);
      acc[1][2] = fmaf(a.y, b.z, acc[1][2]);
      acc[1][3] = fmaf(a.y, b.w, acc[1][3]);
      acc[2][0] = fmaf(a.z, b.x, acc[2][0]);
      acc[2][1] = fmaf(a.z, b.y, acc[2][1]);
      acc[2][2] = fmaf(a.z, b.z, acc[2][2]);
      acc[2][3] = fmaf(a.z, b.w, acc[2][3]);
      acc[3][0] = fmaf(a.w, b.x, acc[3][0]);
      acc[3][1] = fmaf(a.w, b.y, acc[3][1]);
      acc[3][2] = fmaf(a.w, b.z, acc[3][2]);
      acc[3][3] = fmaf(a.w, b.w, acc[3][3]);
    }
  }

#pragma unroll
  for (int ii = 0; ii < 4; ++ii) {
    int m = m0 + tm * 4 + ii;
    float d = deg[m];
    float s = (d > 0.f) ? 1.0f / sqrtf(d) : 0.f;
#pragma unroll
    for (int jj = 0; jj < 4; ++jj) {
      int n = n0 + tn * 4 + jj;
      Gt[(size_t)n * M + m] = f2bf(s * acc[ii][jj]);
    }
  }
}

// ---------------- readout ----------------

__global__ void mean_partial(const float* __restrict__ x2, float* __restrict__ macc) {
  int c = threadIdx.x;
  int j0 = blockIdx.x * 16;
  float s = 0.f;
#pragma unroll
  for (int j = 0; j < 16; ++j) s += x2[(size_t)(j0 + j) * CH + c];
  atomicAdd(&macc[c], s);
}

__global__ __launch_bounds__(256) void finalize2(const float* __restrict__ macc, int nr,
                                                 const float* __restrict__ wc,
                                                 const float* __restrict__ bc,
                                                 float* __restrict__ out) {
  __shared__ float semb[256];
  __shared__ float red[256];
  __shared__ float slog[16];
  int c = threadIdx.x;
  float emb = macc[c] / (float)nr;
  red[c] = emb * emb;
  __syncthreads();
  for (int off = 128; off; off >>= 1) {
    if (c < off) red[c] += red[c + off];
    __syncthreads();
  }
  float denom = fmaxf(sqrtf(red[0]), 1e-12f);
  float en = emb / denom;
  semb[c] = en;
  out[c] = en;
  __syncthreads();
  if (c < 10) {
    float l = bc[c];
    for (int t = 0; t < CH; ++t) l = fmaf(semb[t], wc[c * CH + t], l);
    slog[c] = l;
  }
  __syncthreads();
  if (c == 0) {
    float mx = slog[0];
    for (int j = 1; j < 10; ++j) mx = fmaxf(mx, slog[j]);
    float se = 0.f;
    for (int j = 0; j < 10; ++j) se += expf(slog[j] - mx);
    float lse = mx + logf(se);
    for (int j = 0; j < 10; ++j) out[CH + j] = slog[j] - lse;
  }
}

// ---------------- orchestration ----------------

extern "C" void kernel_launch(void* const* d_in, const int* in_sizes, int n_in,
                              void* d_out, int out_size, void* d_ws, size_t ws_size,
                              hipStream_t stream) {
  const float* x  = (const float*)d_in[0];
  const int*   ei = (const int*)d_in[1];
  const float* w0 = (const float*)d_in[2];
  const float* b0 = (const float*)d_in[3];
  const float* w1 = (const float*)d_in[4];
  const float* b1 = (const float*)d_in[5];
  const float* w2 = (const float*)d_in[6];
  const float* b2 = (const float*)d_in[7];
  const float* p1 = (const float*)d_in[8];
  const float* p2 = (const float*)d_in[9];
  const float* wc = (const float*)d_in[10];
  const float* bc = (const float*)d_in[11];
  float* out = (float*)d_out;
  const int N0 = 4096, K1 = 2048, K2 = 1024;
  int E = in_sizes[1] / 2;

  float* W = (float*)d_ws;
  size_t off = 0;
  float* A    = W + off; off += (size_t)N0 * N0;                  // fp32 adj; region reused later:
                                                                  //   Brow (bf16 gathered rows) at A[0..]
                                                                  //   Paux (aug z-partials) at A+8M floats (32MB, to end of A)
  float* deg  = W + off;                                          // deg lives at start of old-Pa slot,
  off += (size_t)K1 * K1;                                         // contiguous with A -> one memset covers both
  ushort* At  = (ushort*)(W + off); off += (size_t)N0 * N0 / 2;   // bf16 transposed adj (per level)
  ushort* Arow = (ushort*)(W + off); off += (size_t)K1 * N0 / 2;  // bf16 gathered rows
  ushort* Brow = (ushort*)A;                                      // aliases A (dead rows consumed first)
  float* Paux = A + (size_t)8 * 1024 * 1024;  // aug partials: augL1 2x2048^2, augL2 8x1024^2 (both 32MB)
  float* Cred = (float*)Arow;  // aliases Arow: agg partials (zn x M x CH) live only
                               // between an agg and its epilogue; Arow dead there.
  float* x0   = W + off; off += (size_t)N0 * CH;
  ushort* Gt  = (ushort*)(W + off); off += (size_t)N0 * CH / 2;
  float* xp  = W + off; off += (size_t)K1 * CH;
  float* x1  = W + off; off += (size_t)K1 * CH;
  float* x2  = W + off; off += (size_t)K2 * CH;
  float* sc  = W + off; off += 4096;
  float* vals = W + off; off += 4096;
  float* macc = W + off; off += 256;
  int* perm1 = (int*)(W + off); off += 4096;
  int* perm2 = (int*)(W + off); off += 4096;

  // ---- build adjacency (+ zero deg in the same memset: deg is contiguous after A) ----
  hipMemsetAsync(A, 0, ((size_t)N0 * N0 + 4096) * 4, stream);
  scatter_edges<<<(E + 255) / 256, 256, 0, stream>>>(ei, E, N0, A);

  // ---- GCN 0 ----
  transpose_deg<0><<<dim3(N0 / 64, N0 / 64), 256, 0, stream>>>(A, N0, At, deg, 1, 0);
  xw_gemm<<<dim3(N0 / 64, CH / 64), 256, 0, stream>>>(x, w0, Gt, N0, deg);
  mfma_nt<64><<<dim3(N0 / 128, CH / 64, 4), 256, 0, stream>>>(At, Gt, Cred, CH, N0, N0 / 4, (size_t)N0 * CH);
  agg_epilogue<<<N0 / 4, 256, 0, stream>>>(Cred, (size_t)N0 * CH, 4, deg, b0, x0, p1, sc, nullptr);

  // ---- pool 1 ----
  topk_rank<<<N0 / 64, 256, N0 * 8, stream>>>(sc, N0, K1, perm1, vals);

  // ---- augment L1 gathers + pool_x (fused), then Paux(z=2) K-split GEMM ----
  gather_fused<<<dim3(N0 / 1024 + N0 / 2048 + 1, K1), 256, 0, stream>>>(
      A, 1, 0, At, perm1, N0, Arow, Brow, x0, vals, xp, N0 / 1024, N0 / 2048);
  mfma_nt<128><<<dim3(K1 / 128, K1 / 128, 2), 256, 0, stream>>>(Arow, Brow, Paux, K1, N0, N0 / 2, (size_t)K1 * K1);

  // ---- GCN 1 (transpose sums the 2 aug partial slices; deg pre-zeroed by epi L0) ----
  transpose_deg<1><<<dim3(K1 / 64, K1 / 64), 256, 0, stream>>>(Paux, K1, At, deg, 2, (size_t)K1 * K1);
  xw_gemm<<<dim3(K1 / 64, CH / 64), 256, 0, stream>>>(xp, w1, Gt, K1, deg);
  mfma_nt<64><<<dim3(K1 / 128, CH / 64, 8), 256, 0, stream>>>(At, Gt, Cred, CH, K1, K1 / 8, (size_t)K1 * CH);
  agg_epilogue<<<K1 / 4, 256, 0, stream>>>(Cred, (size_t)K1 * CH, 8, deg, b1, x1, p2, sc, nullptr);

  // ---- pool 2 ----
  topk_rank<<<K1 / 64, 256, K1 * 8, stream>>>(sc, K1, K2, perm2, vals);

  // ---- augment L2 gathers (sum 2 L1-partial slices) + pool_x (fused); z=8 K-split out ----
  gather_fused<<<dim3(K1 / 1024 + K1 / 2048 + 1, K2), 256, 0, stream>>>(
      Paux, 2, (size_t)K1 * K1, At, perm2, K1, Arow, Brow, x1, vals, xp, K1 / 1024, K1 / 2048);
  mfma_nt<128><<<dim3(K2 / 128, K2 / 128, 8), 256, 0, stream>>>(Arow, Brow, Paux, K2, K1, K1 / 8, (size_t)K2 * K2);

  // ---- GCN 2 (transpose sums the 8 aug partial slices; deg pre-zeroed by epi L1) ----
  transpose_deg<1><<<dim3(K2 / 64, K2 / 64), 256, 0, stream>>>(Paux, K2, At, deg, 8, (size_t)K2 * K2);
  xw_gemm<<<dim3(K2 / 64, CH / 64), 256, 0, stream>>>(xp, w2, Gt, K2, deg);
  mfma_nt<64><<<dim3(K2 / 128, CH / 64, 8), 256, 0, stream>>>(At, Gt, Cred, CH, K2, K2 / 8, (size_t)K2 * CH);
  agg_epilogue<<<K2 / 4, 256, 0, stream>>>(Cred, (size_t)K2 * CH, 8, deg, b2, x2, nullptr, nullptr, macc);

  // ---- readout (macc pre-zeroed by epi L2) ----
  mean_partial<<<K2 / 16, 256, 0, stream>>>(x2, macc);
  finalize2<<<1, 256, 0, stream>>>(macc, K2, wc, bc, out);
}